// Round 2
// baseline (137.149 us; speedup 1.0000x reference)
//
#include <hip/hip_runtime.h>
#include <hip/hip_bf16.h>

// Embedding lookup: out[row, :] = weight[ids[row], :]
// ids: 8192 int32, weight: 32000 x 768 fp32, out: 8192 x 768 fp32.
//
// R1: block-per-row (8192 blocks x 3 waves, 1 load/store per thread) was
// latency/dispatch-bound, not BW-bound. R2: 8 rows per 256-thread block
// (1024 blocks), 6 independent float4 load->store pairs per thread for 6x
// memory-level parallelism. Row stride 192 float4 = 3 x 64, so each wave's
// 64 consecutive j's stay inside one weight row -> every wave load is a
// contiguous 1 KB burst. Stores fully contiguous.

#define DIM_VEC 192            // 768 floats / 4
#define ROWS_PER_BLOCK 8
#define THREADS 256
#define PER_THREAD (ROWS_PER_BLOCK * DIM_VEC / THREADS)   // 6

__global__ __launch_bounds__(THREADS) void embed_gather_kernel(
    const int* __restrict__ ids,
    const float4* __restrict__ weight,
    float4* __restrict__ out) {
    const int row0 = blockIdx.x * ROWS_PER_BLOCK;

    __shared__ int sid[ROWS_PER_BLOCK];
    if (threadIdx.x < ROWS_PER_BLOCK) sid[threadIdx.x] = ids[row0 + threadIdx.x];
    __syncthreads();

    const size_t out_base = (size_t)row0 * DIM_VEC;

    float4 v[PER_THREAD];
#pragma unroll
    for (int k = 0; k < PER_THREAD; ++k) {
        const int j = threadIdx.x + k * THREADS;       // 0..1535 within block
        const int r = j / DIM_VEC;                     // 0..7 (const-folded magic mul)
        const int c = j - r * DIM_VEC;
        v[k] = weight[(size_t)sid[r] * DIM_VEC + c];   // 6 loads in flight
    }
#pragma unroll
    for (int k = 0; k < PER_THREAD; ++k) {
        const int j = threadIdx.x + k * THREADS;
        out[out_base + j] = v[k];
    }
}

extern "C" void kernel_launch(void* const* d_in, const int* in_sizes, int n_in,
                              void* d_out, int out_size, void* d_ws, size_t ws_size,
                              hipStream_t stream) {
    const int* ids = (const int*)d_in[0];        // 8192 int32
    const float4* weight = (const float4*)d_in[1];
    float4* out = (float4*)d_out;

    const int n_rows = in_sizes[0];              // 8192
    const int n_blocks = n_rows / ROWS_PER_BLOCK; // 1024 (8192 divisible by 8)
    embed_gather_kernel<<<n_blocks, THREADS, 0, stream>>>(ids, weight, out);
}